// Round 1
// baseline (206.462 us; speedup 1.0000x reference)
//
#include <hip/hip_runtime.h>
#include <hip/hip_bf16.h>
#include <math.h>

#define NB    16384            // batch rows
#define KDIM  2048             // in_dim
#define NCLS  101              // classes
#define NP    10               // npass
#define NTOT  (NP*NCLS)        // 1010
#define NPAD  1024             // padded N for GEMM
#define PM_SIZE (NB*NCLS)
#define CI    (NCLS*KDIM)      // 206848

#define LSQ2PI 0.9189385332046727f
#define HALF_INV_S2SQ 81377.39570642986f   // 0.5*exp(12) = 0.5/sigma2^2

typedef __bf16 bf16x8 __attribute__((ext_vector_type(8)));
typedef float f32x4 __attribute__((ext_vector_type(4)));
typedef unsigned short u16x8 __attribute__((ext_vector_type(8)));

__device__ __forceinline__ unsigned short f2bf_bits(float f) {
    union { float f; unsigned u; } v; v.f = f;
    unsigned u = v.u;
    unsigned r = u + 0x7FFFu + ((u >> 16) & 1u);   // RNE
    return (unsigned short)(r >> 16);
}

__device__ __forceinline__ float mix_logprob(float v) {
    float q = v * v;
    float lp1 = -LSQ2PI - 0.5f * q;
    float lp2 = -LSQ2PI + 6.0f - HALF_INV_S2SQ * q;
    return __logf(0.5f * __expf(lp1) + 0.5f * __expf(lp2));
}

// ---------------- x -> bf16 ----------------
__global__ void cvt_x_kernel(const float* __restrict__ x, unsigned short* __restrict__ xb) {
    const int t = blockIdx.x * 256 + threadIdx.x;       // 4194304 threads, 8 elems each
    const float4* x4 = (const float4*)x;
    float4 a = x4[2 * t];
    float4 b = x4[2 * t + 1];
    u16x8 o;
    o[0] = f2bf_bits(a.x); o[1] = f2bf_bits(a.y); o[2] = f2bf_bits(a.z); o[3] = f2bf_bits(a.w);
    o[4] = f2bf_bits(b.x); o[5] = f2bf_bits(b.y); o[6] = f2bf_bits(b.z); o[7] = f2bf_bits(b.w);
    *(u16x8*)(xb + 8 * (size_t)t) = o;
}

// ------- sample w, write bf16 B-matrix, reduce prior/posterior -------
__global__ void prep_weights(const float* __restrict__ wmu, const float* __restrict__ wrho,
                             const float* __restrict__ eps_w,
                             unsigned short* __restrict__ wB, float* __restrict__ sums) {
    const int t = blockIdx.x * 256 + threadIdx.x;
    float prior = 0.f, post = 0.f;
    if (t < CI) {
        const float mu = wmu[t];
        const float sigma = log1pf(__expf(wrho[t]));
        const float nls = -__logf(sigma);
        const int c = t / KDIM, i = t & (KDIM - 1);
        #pragma unroll
        for (int n = 0; n < NP; ++n) {
            const float eps = eps_w[(size_t)n * CI + t];
            const float w = fmaf(sigma, eps, mu);
            wB[(size_t)(n * NCLS + c) * KDIM + i] = f2bf_bits(w);
            prior += mix_logprob(w);
            post += nls - LSQ2PI - 0.5f * eps * eps;   // (v-mu)^2/(2s^2) == eps^2/2
        }
    }
    for (int off = 32; off; off >>= 1) {
        prior += __shfl_xor(prior, off);
        post  += __shfl_xor(post, off);
    }
    __shared__ float sp[4], so[4];
    const int wid = threadIdx.x >> 6;
    if ((threadIdx.x & 63) == 0) { sp[wid] = prior; so[wid] = post; }
    __syncthreads();
    if (threadIdx.x == 0) {
        atomicAdd(&sums[0], sp[0] + sp[1] + sp[2] + sp[3]);
        atomicAdd(&sums[1], so[0] + so[1] + so[2] + so[3]);
    }
}

// ------- sample b, build biasN[1024], reduce prior/posterior -------
__global__ void prep_bias(const float* __restrict__ bmu, const float* __restrict__ brho,
                          const float* __restrict__ eps_b,
                          float* __restrict__ biasN, float* __restrict__ sums) {
    const int t = threadIdx.x;    // 1024 threads, 1 block
    float prior = 0.f, post = 0.f, bv = 0.f;
    if (t < NTOT) {
        const int c = t % NCLS;
        const float sigma = log1pf(__expf(brho[c]));
        const float eps = eps_b[t];              // [n,c] flat == t
        bv = fmaf(sigma, eps, bmu[c]);
        prior = mix_logprob(bv);
        post = -LSQ2PI - __logf(sigma) - 0.5f * eps * eps;
    }
    biasN[t] = bv;                                // pad cols get 0
    for (int off = 32; off; off >>= 1) {
        prior += __shfl_xor(prior, off);
        post  += __shfl_xor(post, off);
    }
    __shared__ float sp[16], so[16];
    const int wid = t >> 6;
    if ((t & 63) == 0) { sp[wid] = prior; so[wid] = post; }
    __syncthreads();
    if (t == 0) {
        float a = 0.f, b = 0.f;
        for (int i = 0; i < 16; ++i) { a += sp[i]; b += so[i]; }
        atomicAdd(&sums[0], a);
        atomicAdd(&sums[1], b);
    }
}

__global__ void finalize_scalars(const float* __restrict__ sums, float* __restrict__ out) {
    out[PM_SIZE]     = sums[0] * (1.0f / NP);
    out[PM_SIZE + 1] = sums[1] * (1.0f / NP);
}

// ---------------- bf16 MFMA GEMM: C[m,j] = x[m,:] . wB[j,:] + biasN[j] ----------------
// 128x128 tile, BK=64, 4 waves, 16x16x32 MFMA, global_load_lds w=16,
// LDS XOR-swizzle via pre-swizzled global source (linear LDS dest).
__global__ void __launch_bounds__(256) gemm_bt(
    const unsigned short* __restrict__ A,    // [NB, KDIM] bf16 bits
    const unsigned short* __restrict__ Bm,   // [NPAD, KDIM] bf16 bits
    const float* __restrict__ biasN,
    float* __restrict__ Cout)                // [NB, NPAD] f32
{
    __shared__ __align__(16) unsigned short As[128 * 64];
    __shared__ __align__(16) unsigned short Bs[128 * 64];
    const int t = threadIdx.x;
    const int lane = t & 63;
    const int wid = t >> 6;
    const int wr = wid >> 1, wc = wid & 1;
    const int bm = blockIdx.y * 128;
    const int bn = blockIdx.x * 128;
    const int l15 = lane & 15, l4 = lane >> 4;

    f32x4 acc[4][4] = {};

    for (int k0 = 0; k0 < KDIM; k0 += 64) {
        #pragma unroll
        for (int it = 0; it < 4; ++it) {
            const int flat = it * 256 + t;            // 16B slot index
            const int row = flat >> 3;
            const int jsw = (flat & 7) ^ (row & 7);   // inverse swizzle on the SOURCE
            const unsigned short* ga = A  + (size_t)(bm + row) * KDIM + (k0 + jsw * 8);
            const unsigned short* gb = Bm + (size_t)(bn + row) * KDIM + (k0 + jsw * 8);
            __builtin_amdgcn_global_load_lds(
                (const __attribute__((address_space(1))) void*)ga,
                (__attribute__((address_space(3))) void*)((char*)As + flat * 16), 16, 0, 0);
            __builtin_amdgcn_global_load_lds(
                (const __attribute__((address_space(1))) void*)gb,
                (__attribute__((address_space(3))) void*)((char*)Bs + flat * 16), 16, 0, 0);
        }
        __syncthreads();
        #pragma unroll
        for (int kk = 0; kk < 2; ++kk) {
            bf16x8 af[4], bfr[4];
            #pragma unroll
            for (int m = 0; m < 4; ++m) {
                const int row = wr * 64 + m * 16 + l15;
                const int jr = kk * 4 + l4;
                af[m] = *(const bf16x8*)((const char*)As + row * 128 + ((jr ^ (row & 7)) << 4));
            }
            #pragma unroll
            for (int n = 0; n < 4; ++n) {
                const int row = wc * 64 + n * 16 + l15;
                const int jr = kk * 4 + l4;
                bfr[n] = *(const bf16x8*)((const char*)Bs + row * 128 + ((jr ^ (row & 7)) << 4));
            }
            #pragma unroll
            for (int m = 0; m < 4; ++m)
                #pragma unroll
                for (int n = 0; n < 4; ++n)
                    acc[m][n] = __builtin_amdgcn_mfma_f32_16x16x32_bf16(af[m], bfr[n], acc[m][n], 0, 0, 0);
        }
        __syncthreads();
    }

    #pragma unroll
    for (int n = 0; n < 4; ++n) {
        const int col = bn + wc * 64 + n * 16 + l15;
        const float bv = biasN[col];
        #pragma unroll
        for (int m = 0; m < 4; ++m) {
            const int row0 = bm + wr * 64 + m * 16 + l4 * 4;
            #pragma unroll
            for (int r = 0; r < 4; ++r)
                Cout[(size_t)(row0 + r) * NPAD + col] = acc[m][n][r] + bv;   // C: col=lane&15, row=(lane>>4)*4+r
        }
    }
}

// ---------------- softmax stats: one wave per batch row ----------------
__global__ void stats_kernel(const float* __restrict__ Cout, float* __restrict__ out) {
    const int lane = threadIdx.x & 63;
    const int wid = threadIdx.x >> 6;
    const int b = blockIdx.x * 4 + wid;
    const float* row = Cout + (size_t)b * NPAD;
    float* pm = out;
    float* aleat_out = out + PM_SIZE + 2;
    float* epi_out   = out + PM_SIZE + 2 + NB;

    const bool has2 = lane < (NCLS - 64);   // lane < 37
    float p1s[NP], p2s[NP];
    float pm1 = 0.f, pm2 = 0.f, pb1 = 0.f, pb2 = 0.f, aleat = 0.f;

    for (int n = 0; n < NP; ++n) {
        const float v1 = row[n * NCLS + lane];
        const float v2 = has2 ? row[n * NCLS + 64 + lane] : -INFINITY;
        float mx = fmaxf(v1, v2);
        for (int off = 32; off; off >>= 1) mx = fmaxf(mx, __shfl_xor(mx, off));
        const float e1 = __expf(v1 - mx);
        const float e2 = has2 ? __expf(v2 - mx) : 0.f;
        float s = e1 + e2;
        for (int off = 32; off; off >>= 1) s += __shfl_xor(s, off);
        const float p1 = e1 / s, p2 = e2 / s;
        float spp = p1 + p2, sq = p1 * p1 + p2 * p2;
        for (int off = 32; off; off >>= 1) {
            spp += __shfl_xor(spp, off);
            sq  += __shfl_xor(sq, off);
        }
        aleat += spp - sq;
        pm1 += v1; pm2 += v2;
        pb1 += p1; pb2 += p2;
        p1s[n] = p1; p2s[n] = p2;
    }
    const float inv_n = 1.0f / NP;
    pb1 *= inv_n; pb2 *= inv_n;
    pm[(size_t)b * NCLS + lane] = pm1 * inv_n;
    if (has2) pm[(size_t)b * NCLS + 64 + lane] = pm2 * inv_n;
    float epi = 0.f;
    #pragma unroll
    for (int n = 0; n < NP; ++n) {
        const float d1 = p1s[n] - pb1;
        const float d2 = p2s[n] - pb2;   // 0 for invalid lanes (p2=pb2=0)
        epi += d1 * d1 + d2 * d2;
    }
    for (int off = 32; off; off >>= 1) epi += __shfl_xor(epi, off);
    if (lane == 0) {
        aleat_out[b] = aleat * inv_n;
        epi_out[b]   = epi * inv_n;
    }
}

extern "C" void kernel_launch(void* const* d_in, const int* in_sizes, int n_in,
                              void* d_out, int out_size, void* d_ws, size_t ws_size,
                              hipStream_t stream) {
    const float* x     = (const float*)d_in[0];
    const float* wmu   = (const float*)d_in[1];
    const float* wrho  = (const float*)d_in[2];
    const float* bmu   = (const float*)d_in[3];
    const float* brho  = (const float*)d_in[4];
    const float* eps_w = (const float*)d_in[5];
    const float* eps_b = (const float*)d_in[6];
    float* out = (float*)d_out;

    char* ws = (char*)d_ws;
    const size_t OFF_XB    = 0;                          // 16384*2048*2   = 67108864
    const size_t OFF_WB    = 67108864;                   // 1024*2048*2    =  4194304
    const size_t OFF_COUT  = OFF_WB + 4194304;           // 16384*1024*4   = 67108864
    const size_t OFF_BIASN = OFF_COUT + 67108864;        // 4096
    const size_t OFF_SUMS  = OFF_BIASN + 4096;           // 8

    unsigned short* xb   = (unsigned short*)(ws + OFF_XB);
    unsigned short* wB   = (unsigned short*)(ws + OFF_WB);
    float* Cout  = (float*)(ws + OFF_COUT);
    float* biasN = (float*)(ws + OFF_BIASN);
    float* sums  = (float*)(ws + OFF_SUMS);

    hipMemsetAsync(ws + OFF_SUMS, 0, 8, stream);
    // zero the 14 pad rows of wB so pad output cols are finite
    hipMemsetAsync(ws + OFF_WB + (size_t)NTOT * KDIM * 2, 0, (size_t)(NPAD - NTOT) * KDIM * 2, stream);

    cvt_x_kernel<<<(NB * KDIM / 8) / 256, 256, 0, stream>>>(x, xb);
    prep_weights<<<(CI + 255) / 256, 256, 0, stream>>>(wmu, wrho, eps_w, wB, sums);
    prep_bias<<<1, 1024, 0, stream>>>(bmu, brho, eps_b, biasN, sums);
    finalize_scalars<<<1, 1, 0, stream>>>(sums, out);
    gemm_bt<<<dim3(NPAD / 128, NB / 128), 256, 0, stream>>>(xb, wB, biasN, Cout);
    stats_kernel<<<NB / 4, 256, 0, stream>>>(Cout, out);
}

// Round 2
// 178.723 us; speedup vs baseline: 1.1552x; 1.1552x over previous
//
#include <hip/hip_runtime.h>
#include <hip/hip_bf16.h>
#include <math.h>

#define NB    16384            // batch rows
#define KDIM  2048             // in_dim
#define NCLS  101              // classes
#define NP    10               // npass
#define NTOT  (NP*NCLS)        // 1010
#define NPAD  1024             // padded N for GEMM
#define PM_SIZE (NB*NCLS)
#define CI    (NCLS*KDIM)      // 206848

#define LSQ2PI 0.9189385332046727f
#define HALF_INV_S2SQ 81377.39570642986f   // 0.5*exp(12) = 0.5/sigma2^2

typedef __bf16 bf16x8 __attribute__((ext_vector_type(8)));
typedef float f32x4 __attribute__((ext_vector_type(4)));
typedef unsigned short u16x8 __attribute__((ext_vector_type(8)));

__device__ __forceinline__ unsigned short f2bf_bits(float f) {
    union { float f; unsigned u; } v; v.f = f;
    unsigned u = v.u;
    unsigned r = u + 0x7FFFu + ((u >> 16) & 1u);   // RNE
    return (unsigned short)(r >> 16);
}

__device__ __forceinline__ float mix_logprob(float v) {
    float q = v * v;
    float lp1 = -LSQ2PI - 0.5f * q;
    float lp2 = -LSQ2PI + 6.0f - HALF_INV_S2SQ * q;
    return __logf(0.5f * __expf(lp1) + 0.5f * __expf(lp2));
}

// ---------------- x -> bf16 ----------------
__global__ void cvt_x_kernel(const float* __restrict__ x, unsigned short* __restrict__ xb) {
    const int t = blockIdx.x * 256 + threadIdx.x;
    const float4* x4 = (const float4*)x;
    float4 a = x4[2 * t];
    float4 b = x4[2 * t + 1];
    u16x8 o;
    o[0] = f2bf_bits(a.x); o[1] = f2bf_bits(a.y); o[2] = f2bf_bits(a.z); o[3] = f2bf_bits(a.w);
    o[4] = f2bf_bits(b.x); o[5] = f2bf_bits(b.y); o[6] = f2bf_bits(b.z); o[7] = f2bf_bits(b.w);
    *(u16x8*)(xb + 8 * (size_t)t) = o;
}

// ------- sample w, write bf16 B-matrix, reduce prior/posterior -------
__global__ void prep_weights(const float* __restrict__ wmu, const float* __restrict__ wrho,
                             const float* __restrict__ eps_w,
                             unsigned short* __restrict__ wB, float* __restrict__ sums) {
    const int t = blockIdx.x * 256 + threadIdx.x;
    float prior = 0.f, post = 0.f;
    if (t < CI) {
        const float mu = wmu[t];
        const float sigma = log1pf(__expf(wrho[t]));
        const float nls = -__logf(sigma);
        const int c = t / KDIM, i = t & (KDIM - 1);
        #pragma unroll
        for (int n = 0; n < NP; ++n) {
            const float eps = eps_w[(size_t)n * CI + t];
            const float w = fmaf(sigma, eps, mu);
            wB[(size_t)(n * NCLS + c) * KDIM + i] = f2bf_bits(w);
            prior += mix_logprob(w);
            post += nls - LSQ2PI - 0.5f * eps * eps;
        }
    }
    for (int off = 32; off; off >>= 1) {
        prior += __shfl_xor(prior, off);
        post  += __shfl_xor(post, off);
    }
    __shared__ float sp[4], so[4];
    const int wid = threadIdx.x >> 6;
    if ((threadIdx.x & 63) == 0) { sp[wid] = prior; so[wid] = post; }
    __syncthreads();
    if (threadIdx.x == 0) {
        atomicAdd(&sums[0], sp[0] + sp[1] + sp[2] + sp[3]);
        atomicAdd(&sums[1], so[0] + so[1] + so[2] + so[3]);
    }
}

// ------- sample b, build biasN[1024], reduce prior/posterior -------
__global__ void prep_bias(const float* __restrict__ bmu, const float* __restrict__ brho,
                          const float* __restrict__ eps_b,
                          float* __restrict__ biasN, float* __restrict__ sums) {
    const int t = threadIdx.x;
    float prior = 0.f, post = 0.f, bv = 0.f;
    if (t < NTOT) {
        const int c = t % NCLS;
        const float sigma = log1pf(__expf(brho[c]));
        const float eps = eps_b[t];
        bv = fmaf(sigma, eps, bmu[c]);
        prior = mix_logprob(bv);
        post = -LSQ2PI - __logf(sigma) - 0.5f * eps * eps;
    }
    biasN[t] = bv;
    for (int off = 32; off; off >>= 1) {
        prior += __shfl_xor(prior, off);
        post  += __shfl_xor(post, off);
    }
    __shared__ float sp[16], so[16];
    const int wid = t >> 6;
    if ((t & 63) == 0) { sp[wid] = prior; so[wid] = post; }
    __syncthreads();
    if (t == 0) {
        float a = 0.f, b = 0.f;
        for (int i = 0; i < 16; ++i) { a += sp[i]; b += so[i]; }
        atomicAdd(&sums[0], a);
        atomicAdd(&sums[1], b);
    }
}

__global__ void finalize_scalars(const float* __restrict__ sums, float* __restrict__ out) {
    out[PM_SIZE]     = sums[0] * (1.0f / NP);
    out[PM_SIZE + 1] = sums[1] * (1.0f / NP);
}

// =============== 256x256 8-phase bf16 MFMA GEMM ===============
// BM=BN=256, BK=64, 512 threads (8 waves, 2M x 4N), LDS 128 KiB
// (2 dbuf x {A0,A1,B0,B1} halves of 128x64 bf16). Per wave: 128x64 output,
// acc[8][4] f32x4. Per K-tile: 4 phases, each {ds_read subtile | stage one
// half-tile via global_load_lds | barrier | 16 MFMA | barrier}; counted
// vmcnt(6) once per K-tile (never 0 in main loop).
// LDS regions: reg = buf*4 + {0:A-half0, 1:A-half1, 2:B-half0, 3:B-half1},
// each 16384 B. XOR swizzle: LDS slot s of row holds global 16B-slot
// s^(row&7); achieved with linear LDS dest + inverse-swizzled global source.
__device__ __forceinline__ void stage_half(const unsigned short* __restrict__ G,
                                           int grow0, int k0, int lds_byte_base,
                                           int tid, char* ldsp) {
    #pragma unroll
    for (int l = 0; l < 2; ++l) {
        const int flat = l * 512 + tid;            // 16B slot index 0..1023
        const int row = flat >> 3, j = flat & 7;
        const int jsw = j ^ (row & 7);
        const unsigned short* src = G + (size_t)(grow0 + row) * KDIM + k0 + jsw * 8;
        __builtin_amdgcn_global_load_lds(
            (const __attribute__((address_space(1))) void*)src,
            (__attribute__((address_space(3))) void*)(ldsp + lds_byte_base + flat * 16),
            16, 0, 0);
    }
}

#define STAGE_A(buf, half, tt) stage_half(A,  bm + (half) * 128, (tt) * 64, ((buf) * 4 + (half)) * 16384, tid, ldsp)
#define STAGE_B(buf, half, tt) stage_half(Bm, bn + (half) * 128, (tt) * 64, ((buf) * 4 + 2 + (half)) * 16384, tid, ldsp)

#define LDA(mf, buf) do { \
    const int rowh_ = (mf) * 16 + l15; \
    const char* p_ = ldsp + ((buf) * 4 + aregion) * 16384 + rowh_ * 128; \
    const int sw_ = (rowh_ & 7) << 4; \
    af[(mf) & 3][0] = *(const bf16x8*)(p_ + ((l4 << 4) ^ sw_)); \
    af[(mf) & 3][1] = *(const bf16x8*)(p_ + (((4 + l4) << 4) ^ sw_)); \
} while (0)

#define LDB(nf, buf) do { \
    const int rowh_ = (wc & 1) * 64 + (nf) * 16 + l15; \
    const char* p_ = ldsp + ((buf) * 4 + bregion) * 16384 + rowh_ * 128; \
    const int sw_ = (rowh_ & 7) << 4; \
    bf[nf][0] = *(const bf16x8*)(p_ + ((l4 << 4) ^ sw_)); \
    bf[nf][1] = *(const bf16x8*)(p_ + (((4 + l4) << 4) ^ sw_)); \
} while (0)

#define MM(mh, nh) do { \
    __builtin_amdgcn_s_setprio(1); \
    _Pragma("unroll") \
    for (int mi = 0; mi < 4; ++mi) \
        _Pragma("unroll") \
        for (int ni = 0; ni < 2; ++ni) \
            _Pragma("unroll") \
            for (int kk = 0; kk < 2; ++kk) \
                acc[(mh) * 4 + mi][(nh) * 2 + ni] = __builtin_amdgcn_mfma_f32_16x16x32_bf16( \
                    af[mi][kk], bf[(nh) * 2 + ni][kk], acc[(mh) * 4 + mi][(nh) * 2 + ni], 0, 0, 0); \
    __builtin_amdgcn_s_setprio(0); \
} while (0)

#define SBAR() do { \
    __builtin_amdgcn_sched_barrier(0); \
    __builtin_amdgcn_s_barrier(); \
    __builtin_amdgcn_sched_barrier(0); \
} while (0)

__global__ void __launch_bounds__(512, 2) gemm8(
    const unsigned short* __restrict__ A,    // [NB, KDIM] bf16 bits
    const unsigned short* __restrict__ Bm,   // [NPAD, KDIM] bf16 bits
    const float* __restrict__ biasN,
    float* __restrict__ Cout)                // [NB, NPAD] f32
{
    __shared__ __align__(16) unsigned short lds[65536];   // 128 KiB
    char* ldsp = (char*)lds;
    const int tid = threadIdx.x;
    const int lane = tid & 63, wid = tid >> 6;
    const int wr = wid >> 2, wc = wid & 3;               // 2M x 4N waves
    const int l15 = lane & 15, l4 = lane >> 4;

    // XCD-chunked swizzle: blocks b==x (mod 8) run on XCD x; give each XCD
    // a contiguous wg range so the 4 N-blocks of an M-strip share its L2.
    const int b = blockIdx.x;
    const int wg = (b & 7) * 32 + (b >> 3);              // bijective, 256 blocks
    const int bm = (wg >> 2) * 256;
    const int bn = (wg & 3) * 256;

    const int aregion = wr;          // this wave's A half lives in region wr
    const int bregion = 2 + (wc >> 1);

    f32x4 acc[8][4] = {{}};
    bf16x8 af[4][2], bf[4][2];

    // ---- prologue: tile0 fully + tile1 {A0,B0,B1}; A1(1) staged at P1(t=0)
    STAGE_A(0, 0, 0); STAGE_A(0, 1, 0); STAGE_B(0, 0, 0); STAGE_B(0, 1, 0);
    STAGE_A(1, 0, 1); STAGE_B(1, 0, 1); STAGE_B(1, 1, 1);
    __builtin_amdgcn_sched_barrier(0);
    asm volatile("s_waitcnt vmcnt(6)");
    SBAR();

    for (int t = 0; t < 32; ++t) {
        const int buf = t & 1, nbuf = buf ^ 1;
        // --- P1: read A(mh0)+B(nh0) of t; stage A1(t+1)
        LDA(0, buf); LDA(1, buf); LDA(2, buf); LDA(3, buf);
        LDB(0, buf); LDB(1, buf);
        if (t + 1 < 32) STAGE_A(nbuf, 1, t + 1);
        SBAR();
        MM(0, 0);
        SBAR();
        // --- P2: read B(nh1)
        LDB(2, buf); LDB(3, buf);
        SBAR();
        MM(0, 1);
        SBAR();
        // --- P3: read A(mh1); stage B0(t+2)
        LDA(4, buf); LDA(5, buf); LDA(6, buf); LDA(7, buf);
        if (t + 2 < 32) STAGE_B(buf, 0, t + 2);
        SBAR();
        MM(1, 1);
        SBAR();
        // --- P4: no reads; stage A0(t+2), B1(t+2); counted vmcnt gate
        if (t + 2 < 32) { STAGE_A(buf, 0, t + 2); STAGE_B(buf, 1, t + 2); }
        SBAR();
        MM(1, 0);
        __builtin_amdgcn_sched_barrier(0);
        if (t < 30) { asm volatile("s_waitcnt vmcnt(6)"); }
        else        { asm volatile("s_waitcnt vmcnt(0)"); }
        __builtin_amdgcn_sched_barrier(0);
        __builtin_amdgcn_s_barrier();
        __builtin_amdgcn_sched_barrier(0);
    }

    // ---- epilogue: bias + store f32 (C frag: col=lane&15, row=(lane>>4)*4+r)
    #pragma unroll
    for (int n = 0; n < 4; ++n) {
        const int col = bn + wc * 64 + n * 16 + l15;
        const float bv = biasN[col];
        #pragma unroll
        for (int m = 0; m < 8; ++m) {
            const int row0 = bm + wr * 128 + m * 16 + l4 * 4;
            #pragma unroll
            for (int r = 0; r < 4; ++r)
                Cout[(size_t)(row0 + r) * NPAD + col] = acc[m][n][r] + bv;
        }
    }
}

// ---------------- softmax stats: one wave per batch row ----------------
__global__ void stats_kernel(const float* __restrict__ Cout, float* __restrict__ out) {
    const int lane = threadIdx.x & 63;
    const int wid = threadIdx.x >> 6;
    const int b = blockIdx.x * 4 + wid;
    const float* row = Cout + (size_t)b * NPAD;
    float* pm = out;
    float* aleat_out = out + PM_SIZE + 2;
    float* epi_out   = out + PM_SIZE + 2 + NB;

    const bool has2 = lane < (NCLS - 64);
    float p1s[NP], p2s[NP];
    float pm1 = 0.f, pm2 = 0.f, pb1 = 0.f, pb2 = 0.f, aleat = 0.f;

    for (int n = 0; n < NP; ++n) {
        const float v1 = row[n * NCLS + lane];
        const float v2 = has2 ? row[n * NCLS + 64 + lane] : -INFINITY;
        float mx = fmaxf(v1, v2);
        for (int off = 32; off; off >>= 1) mx = fmaxf(mx, __shfl_xor(mx, off));
        const float e1 = __expf(v1 - mx);
        const float e2 = has2 ? __expf(v2 - mx) : 0.f;
        float s = e1 + e2;
        for (int off = 32; off; off >>= 1) s += __shfl_xor(s, off);
        const float p1 = e1 / s, p2 = e2 / s;
        float spp = p1 + p2, sq = p1 * p1 + p2 * p2;
        for (int off = 32; off; off >>= 1) {
            spp += __shfl_xor(spp, off);
            sq  += __shfl_xor(sq, off);
        }
        aleat += spp - sq;
        pm1 += v1; pm2 += v2;
        pb1 += p1; pb2 += p2;
        p1s[n] = p1; p2s[n] = p2;
    }
    const float inv_n = 1.0f / NP;
    pb1 *= inv_n; pb2 *= inv_n;
    pm[(size_t)b * NCLS + lane] = pm1 * inv_n;
    if (has2) pm[(size_t)b * NCLS + 64 + lane] = pm2 * inv_n;
    float epi = 0.f;
    #pragma unroll
    for (int n = 0; n < NP; ++n) {
        const float d1 = p1s[n] - pb1;
        const float d2 = p2s[n] - pb2;
        epi += d1 * d1 + d2 * d2;
    }
    for (int off = 32; off; off >>= 1) epi += __shfl_xor(epi, off);
    if (lane == 0) {
        aleat_out[b] = aleat * inv_n;
        epi_out[b]   = epi * inv_n;
    }
}

extern "C" void kernel_launch(void* const* d_in, const int* in_sizes, int n_in,
                              void* d_out, int out_size, void* d_ws, size_t ws_size,
                              hipStream_t stream) {
    const float* x     = (const float*)d_in[0];
    const float* wmu   = (const float*)d_in[1];
    const float* wrho  = (const float*)d_in[2];
    const float* bmu   = (const float*)d_in[3];
    const float* brho  = (const float*)d_in[4];
    const float* eps_w = (const float*)d_in[5];
    const float* eps_b = (const float*)d_in[6];
    float* out = (float*)d_out;

    char* ws = (char*)d_ws;
    const size_t OFF_XB    = 0;                          // 16384*2048*2   = 67108864
    const size_t OFF_WB    = 67108864;                   // 1024*2048*2    =  4194304
    const size_t OFF_COUT  = OFF_WB + 4194304;           // 16384*1024*4   = 67108864
    const size_t OFF_BIASN = OFF_COUT + 67108864;        // 4096
    const size_t OFF_SUMS  = OFF_BIASN + 4096;           // 8

    unsigned short* xb   = (unsigned short*)(ws + OFF_XB);
    unsigned short* wB   = (unsigned short*)(ws + OFF_WB);
    float* Cout  = (float*)(ws + OFF_COUT);
    float* biasN = (float*)(ws + OFF_BIASN);
    float* sums  = (float*)(ws + OFF_SUMS);

    hipMemsetAsync(ws + OFF_SUMS, 0, 8, stream);
    hipMemsetAsync(ws + OFF_WB + (size_t)NTOT * KDIM * 2, 0, (size_t)(NPAD - NTOT) * KDIM * 2, stream);

    cvt_x_kernel<<<(NB * KDIM / 8) / 256, 256, 0, stream>>>(x, xb);
    prep_weights<<<(CI + 255) / 256, 256, 0, stream>>>(wmu, wrho, eps_w, wB, sums);
    prep_bias<<<1, 1024, 0, stream>>>(bmu, brho, eps_b, biasN, sums);
    finalize_scalars<<<1, 1, 0, stream>>>(sums, out);
    gemm8<<<256, 512, 0, stream>>>(xb, wB, biasN, Cout);
    stats_kernel<<<NB / 4, 256, 0, stream>>>(Cout, out);
}

// Round 3
// 149.250 us; speedup vs baseline: 1.3833x; 1.1975x over previous
//
#include <hip/hip_runtime.h>
#include <hip/hip_bf16.h>
#include <math.h>

#define NB    16384            // batch rows
#define KDIM  2048             // in_dim
#define NCLS  101              // classes
#define NP    10               // npass
#define NTOT  (NP*NCLS)        // 1010
#define NPAD  1024             // padded N for GEMM
#define PM_SIZE (NB*NCLS)
#define CI    (NCLS*KDIM)      // 206848
#define NBLK_PW ((CI + 255) / 256)   // 808 blocks in prep_weights
#define PAD_ELEMS ((NPAD - NTOT) * KDIM)  // 28672

#define LSQ2PI 0.9189385332046727f
#define HALF_INV_S2SQ 81377.39570642986f   // 0.5*exp(12) = 0.5/sigma2^2

typedef __bf16 bf16x8 __attribute__((ext_vector_type(8)));
typedef float f32x4 __attribute__((ext_vector_type(4)));

__device__ __forceinline__ unsigned short f2bf_bits(float f) {
    union { float f; unsigned u; } v; v.f = f;
    unsigned u = v.u;
    unsigned r = u + 0x7FFFu + ((u >> 16) & 1u);   // RNE
    return (unsigned short)(r >> 16);
}

__device__ __forceinline__ bf16x8 cvt8(float4 a, float4 b) {
    bf16x8 r;
    r[0] = (__bf16)a.x; r[1] = (__bf16)a.y; r[2] = (__bf16)a.z; r[3] = (__bf16)a.w;
    r[4] = (__bf16)b.x; r[5] = (__bf16)b.y; r[6] = (__bf16)b.z; r[7] = (__bf16)b.w;
    return r;
}

__device__ __forceinline__ float mix_logprob(float v) {
    float q = v * v;
    float lp1 = -LSQ2PI - 0.5f * q;
    float lp2 = -LSQ2PI + 6.0f - HALF_INV_S2SQ * q;
    return __logf(0.5f * __expf(lp1) + 0.5f * __expf(lp2));
}

// ------- sample w, write bf16 B-matrix, per-block partial prior/posterior -------
__global__ void prep_weights(const float* __restrict__ wmu, const float* __restrict__ wrho,
                             const float* __restrict__ eps_w,
                             unsigned short* __restrict__ wB, float* __restrict__ partials) {
    const int t = blockIdx.x * 256 + threadIdx.x;
    // zero wB pad rows (cols NTOT..NPAD-1 of the GEMM B matrix)
    if (t < PAD_ELEMS) wB[(size_t)NTOT * KDIM + t] = 0;
    float prior = 0.f, post = 0.f;
    if (t < CI) {
        const float mu = wmu[t];
        const float sigma = log1pf(__expf(wrho[t]));
        const float nls = -__logf(sigma);
        const int c = t / KDIM, i = t & (KDIM - 1);
        #pragma unroll
        for (int n = 0; n < NP; ++n) {
            const float eps = eps_w[(size_t)n * CI + t];
            const float w = fmaf(sigma, eps, mu);
            wB[(size_t)(n * NCLS + c) * KDIM + i] = f2bf_bits(w);
            prior += mix_logprob(w);
            post += nls - LSQ2PI - 0.5f * eps * eps;
        }
    }
    for (int off = 32; off; off >>= 1) {
        prior += __shfl_xor(prior, off);
        post  += __shfl_xor(post, off);
    }
    __shared__ float sp[4], so[4];
    const int wid = threadIdx.x >> 6;
    if ((threadIdx.x & 63) == 0) { sp[wid] = prior; so[wid] = post; }
    __syncthreads();
    if (threadIdx.x == 0) {
        partials[blockIdx.x * 2]     = sp[0] + sp[1] + sp[2] + sp[3];
        partials[blockIdx.x * 2 + 1] = so[0] + so[1] + so[2] + so[3];
    }
}

// ------- sample b, build biasN[1024], reduce partials + bias terms, write scalars -------
__global__ void prep_bias(const float* __restrict__ bmu, const float* __restrict__ brho,
                          const float* __restrict__ eps_b, const float* __restrict__ partials,
                          float* __restrict__ biasN, float* __restrict__ out) {
    const int t = threadIdx.x;    // 1024 threads, 1 block
    float prior = 0.f, post = 0.f, bv = 0.f;
    if (t < NTOT) {
        const int c = t % NCLS;
        const float sigma = log1pf(__expf(brho[c]));
        const float eps = eps_b[t];
        bv = fmaf(sigma, eps, bmu[c]);
        prior = mix_logprob(bv);
        post = -LSQ2PI - __logf(sigma) - 0.5f * eps * eps;
    }
    biasN[t] = bv;
    if (t < NBLK_PW) { prior += partials[2 * t]; post += partials[2 * t + 1]; }
    for (int off = 32; off; off >>= 1) {
        prior += __shfl_xor(prior, off);
        post  += __shfl_xor(post, off);
    }
    __shared__ float sp[16], so[16];
    const int wid = t >> 6;
    if ((t & 63) == 0) { sp[wid] = prior; so[wid] = post; }
    __syncthreads();
    if (t == 0) {
        float a = 0.f, b = 0.f;
        for (int i = 0; i < 16; ++i) { a += sp[i]; b += so[i]; }
        out[PM_SIZE]     = a * (1.0f / NP);
        out[PM_SIZE + 1] = b * (1.0f / NP);
    }
}

// =============== 256x256 8-phase bf16 MFMA GEMM, fused f32->bf16 A-staging ===============
// BM=BN=256, BK=64, 512 threads (8 waves, 2M x 4N), LDS 128 KiB.
// A (x, f32) is reg-staged: 8x global_load_dwordx4 issued in P1, converted and
// ds_write_b128 (XOR-swizzled) in P3/P4 after counted vmcnt. B (bf16) stays on
// global_load_lds with inverse-swizzled source. vmcnt ledger (steady state):
//   entry: B(t+1) 4 outstanding
//   P1 issues Ah1 4 + Ah0 4 -> 12; P3 issues B0(t+2) 2 -> 14, wait vmcnt(6)
//   (drains B(t+1)+Ah1); P4 issues B1(t+2) 2 -> 8, wait vmcnt(4) (drains Ah0).
//   End-of-tile: lgkmcnt(0) only (ds_write visibility); 4 B(t+2) stay in flight.
__device__ __forceinline__ void stage_half(const unsigned short* __restrict__ G,
                                           int grow0, int k0, int lds_byte_base,
                                           int tid, char* ldsp) {
    #pragma unroll
    for (int l = 0; l < 2; ++l) {
        const int flat = l * 512 + tid;            // 16B slot index 0..1023
        const int row = flat >> 3, j = flat & 7;
        const int jsw = j ^ (row & 7);
        const unsigned short* src = G + (size_t)(grow0 + row) * KDIM + k0 + jsw * 8;
        __builtin_amdgcn_global_load_lds(
            (const __attribute__((address_space(1))) void*)src,
            (__attribute__((address_space(3))) void*)(ldsp + lds_byte_base + flat * 16),
            16, 0, 0);
    }
}

#define STAGE_B(buf, half, tt) stage_half(Bm, bn + (half) * 128, (tt) * 64, ((buf) * 4 + 2 + (half)) * 16384, tid, ldsp)

#define A_LOAD(dst, half, tt) do { \
    const float* p0_ = X + (size_t)(bm + (half) * 128 + ar0) * KDIM + (tt) * 64 + ac0; \
    const float* p1_ = X + (size_t)(bm + (half) * 128 + ar1) * KDIM + (tt) * 64 + ac1; \
    dst[0] = *(const float4*)p0_; dst[1] = *(const float4*)(p0_ + 4); \
    dst[2] = *(const float4*)p1_; dst[3] = *(const float4*)(p1_ + 4); \
} while (0)

#define A_WRITE(src, half, buf_) do { \
    char* base_ = ldsp + (((buf_) * 4 + (half)) * 16384); \
    *(bf16x8*)(base_ + aw0) = cvt8(src[0], src[1]); \
    *(bf16x8*)(base_ + aw1) = cvt8(src[2], src[3]); \
} while (0)

#define LDA(mf, buf) do { \
    const int rowh_ = (mf) * 16 + l15; \
    const char* p_ = ldsp + ((buf) * 4 + aregion) * 16384 + rowh_ * 128; \
    const int sw_ = (rowh_ & 7) << 4; \
    af[(mf) & 3][0] = *(const bf16x8*)(p_ + ((l4 << 4) ^ sw_)); \
    af[(mf) & 3][1] = *(const bf16x8*)(p_ + (((4 + l4) << 4) ^ sw_)); \
} while (0)

#define LDB(nf, buf) do { \
    const int rowh_ = (wc & 1) * 64 + (nf) * 16 + l15; \
    const char* p_ = ldsp + ((buf) * 4 + bregion) * 16384 + rowh_ * 128; \
    const int sw_ = (rowh_ & 7) << 4; \
    bf[nf][0] = *(const bf16x8*)(p_ + ((l4 << 4) ^ sw_)); \
    bf[nf][1] = *(const bf16x8*)(p_ + (((4 + l4) << 4) ^ sw_)); \
} while (0)

#define MM(mh, nh) do { \
    __builtin_amdgcn_s_setprio(1); \
    _Pragma("unroll") \
    for (int mi = 0; mi < 4; ++mi) \
        _Pragma("unroll") \
        for (int ni = 0; ni < 2; ++ni) \
            _Pragma("unroll") \
            for (int kk = 0; kk < 2; ++kk) \
                acc[(mh) * 4 + mi][(nh) * 2 + ni] = __builtin_amdgcn_mfma_f32_16x16x32_bf16( \
                    af[mi][kk], bf[(nh) * 2 + ni][kk], acc[(mh) * 4 + mi][(nh) * 2 + ni], 0, 0, 0); \
    __builtin_amdgcn_s_setprio(0); \
} while (0)

#define SBAR() do { \
    __builtin_amdgcn_sched_barrier(0); \
    __builtin_amdgcn_s_barrier(); \
    __builtin_amdgcn_sched_barrier(0); \
} while (0)

__global__ void __launch_bounds__(512, 2) gemm8(
    const float* __restrict__ X,             // [NB, KDIM] f32
    const unsigned short* __restrict__ Bm,   // [NPAD, KDIM] bf16 bits
    const float* __restrict__ biasN,
    float* __restrict__ Cout)                // [NB, NPAD] f32
{
    __shared__ __align__(16) unsigned short lds[65536];   // 128 KiB
    char* ldsp = (char*)lds;
    const int tid = threadIdx.x;
    const int lane = tid & 63, wid = tid >> 6;
    const int wr = wid >> 2, wc = wid & 3;               // 2M x 4N waves
    const int l15 = lane & 15, l4 = lane >> 4;

    const int b = blockIdx.x;
    const int wg = (b & 7) * 32 + (b >> 3);              // bijective XCD swizzle, 256 blocks
    const int bm = (wg >> 2) * 256;
    const int bn = (wg & 3) * 256;

    const int aregion = wr;
    const int bregion = 2 + (wc >> 1);

    // A staging geometry: 2 x 16B slots per thread per half (128 rows x 8 slots)
    const int s0 = tid * 2, s1 = s0 + 1;
    const int ar0 = s0 >> 3, ac0 = (s0 & 7) * 8;
    const int ar1 = s1 >> 3, ac1 = (s1 & 7) * 8;
    const int aw0 = ar0 * 128 + (((s0 & 7) ^ (ar0 & 7)) << 4);
    const int aw1 = ar1 * 128 + (((s1 & 7) ^ (ar1 & 7)) << 4);

    f32x4 acc[8][4] = {{}};
    bf16x8 af[4][2], bf[4][2];
    float4 aH0[4], aH1[4];

    // ---- prologue: A(0) via regs, B(0)+B(1) via gload_lds
    A_LOAD(aH1, 1, 0);
    A_LOAD(aH0, 0, 0);
    STAGE_B(0, 0, 0); STAGE_B(0, 1, 0);
    STAGE_B(1, 0, 1); STAGE_B(1, 1, 1);
    __builtin_amdgcn_sched_barrier(0);
    asm volatile("s_waitcnt vmcnt(8)");     // A(0) loads done (8 B gloads remain)
    __builtin_amdgcn_sched_barrier(0);
    A_WRITE(aH1, 1, 0);
    A_WRITE(aH0, 0, 0);
    __builtin_amdgcn_sched_barrier(0);
    asm volatile("s_waitcnt vmcnt(4) lgkmcnt(0)");   // B(0) landed, A writes drained
    __builtin_amdgcn_s_barrier();
    __builtin_amdgcn_sched_barrier(0);

    for (int t = 0; t < 32; ++t) {
        const int buf = t & 1, nbuf = buf ^ 1;
        const bool pf = (t + 1 < 32);
        // --- P1: read A(mh0)+B(nh0); issue A(t+1) reg loads (both halves)
        LDA(0, buf); LDA(1, buf); LDA(2, buf); LDA(3, buf);
        LDB(0, buf); LDB(1, buf);
        if (pf) { A_LOAD(aH1, 1, t + 1); A_LOAD(aH0, 0, t + 1); }
        SBAR();
        MM(0, 0);
        SBAR();
        // --- P2: read B(nh1)
        LDB(2, buf); LDB(3, buf);
        SBAR();
        MM(0, 1);
        SBAR();
        // --- P3: read A(mh1); stage B0(t+2); wait Ah1; write A1(t+1)
        LDA(4, buf); LDA(5, buf); LDA(6, buf); LDA(7, buf);
        if (t + 2 < 32) STAGE_B(buf, 0, t + 2);
        __builtin_amdgcn_sched_barrier(0);
        if (t < 30) { asm volatile("s_waitcnt vmcnt(6)"); }
        else        { asm volatile("s_waitcnt vmcnt(0)"); }
        __builtin_amdgcn_sched_barrier(0);
        if (pf) A_WRITE(aH1, 1, nbuf);
        SBAR();
        MM(1, 1);
        SBAR();
        // --- P4: stage B1(t+2); wait Ah0; write A0(t+1)
        if (t + 2 < 32) STAGE_B(buf, 1, t + 2);
        __builtin_amdgcn_sched_barrier(0);
        if (t < 30) { asm volatile("s_waitcnt vmcnt(4)"); }
        else        { asm volatile("s_waitcnt vmcnt(0)"); }
        __builtin_amdgcn_sched_barrier(0);
        if (pf) A_WRITE(aH0, 0, nbuf);
        SBAR();
        MM(1, 0);
        __builtin_amdgcn_sched_barrier(0);
        asm volatile("s_waitcnt lgkmcnt(0)");   // drain A ds_writes before barrier
        __builtin_amdgcn_s_barrier();
        __builtin_amdgcn_sched_barrier(0);
    }

    // ---- epilogue: bias + store f32 (C frag: col=lane&15, row=(lane>>4)*4+r)
    #pragma unroll
    for (int n = 0; n < 4; ++n) {
        const int col = bn + wc * 64 + n * 16 + l15;
        const float bv = biasN[col];
        #pragma unroll
        for (int m = 0; m < 8; ++m) {
            const int row0 = bm + wr * 128 + m * 16 + l4 * 4;
            #pragma unroll
            for (int r = 0; r < 4; ++r)
                Cout[(size_t)(row0 + r) * NPAD + col] = acc[m][n][r] + bv;
        }
    }
}

// ---------------- softmax stats: one wave per batch row ----------------
__global__ void stats_kernel(const float* __restrict__ Cout, float* __restrict__ out) {
    const int lane = threadIdx.x & 63;
    const int wid = threadIdx.x >> 6;
    const int b = blockIdx.x * 4 + wid;
    const float* row = Cout + (size_t)b * NPAD;
    float* pm = out;
    float* aleat_out = out + PM_SIZE + 2;
    float* epi_out   = out + PM_SIZE + 2 + NB;

    const bool has2 = lane < (NCLS - 64);
    float p1s[NP], p2s[NP];
    float pm1 = 0.f, pm2 = 0.f, pb1 = 0.f, pb2 = 0.f, aleat = 0.f;

    for (int n = 0; n < NP; ++n) {
        const float v1 = row[n * NCLS + lane];
        const float v2 = has2 ? row[n * NCLS + 64 + lane] : -INFINITY;
        float mx = fmaxf(v1, v2);
        for (int off = 32; off; off >>= 1) mx = fmaxf(mx, __shfl_xor(mx, off));
        const float e1 = __expf(v1 - mx);
        const float e2 = has2 ? __expf(v2 - mx) : 0.f;
        float s = e1 + e2;
        for (int off = 32; off; off >>= 1) s += __shfl_xor(s, off);
        const float p1 = e1 / s, p2 = e2 / s;
        float spp = p1 + p2, sq = p1 * p1 + p2 * p2;
        for (int off = 32; off; off >>= 1) {
            spp += __shfl_xor(spp, off);
            sq  += __shfl_xor(sq, off);
        }
        aleat += spp - sq;
        pm1 += v1; pm2 += v2;
        pb1 += p1; pb2 += p2;
        p1s[n] = p1; p2s[n] = p2;
    }
    const float inv_n = 1.0f / NP;
    pb1 *= inv_n; pb2 *= inv_n;
    pm[(size_t)b * NCLS + lane] = pm1 * inv_n;
    if (has2) pm[(size_t)b * NCLS + 64 + lane] = pm2 * inv_n;
    float epi = 0.f;
    #pragma unroll
    for (int n = 0; n < NP; ++n) {
        const float d1 = p1s[n] - pb1;
        const float d2 = p2s[n] - pb2;
        epi += d1 * d1 + d2 * d2;
    }
    for (int off = 32; off; off >>= 1) epi += __shfl_xor(epi, off);
    if (lane == 0) {
        aleat_out[b] = aleat * inv_n;
        epi_out[b]   = epi * inv_n;
    }
}

extern "C" void kernel_launch(void* const* d_in, const int* in_sizes, int n_in,
                              void* d_out, int out_size, void* d_ws, size_t ws_size,
                              hipStream_t stream) {
    const float* x     = (const float*)d_in[0];
    const float* wmu   = (const float*)d_in[1];
    const float* wrho  = (const float*)d_in[2];
    const float* bmu   = (const float*)d_in[3];
    const float* brho  = (const float*)d_in[4];
    const float* eps_w = (const float*)d_in[5];
    const float* eps_b = (const float*)d_in[6];
    float* out = (float*)d_out;

    char* ws = (char*)d_ws;
    const size_t OFF_WB    = 0;                          // 1024*2048*2  = 4194304
    const size_t OFF_COUT  = OFF_WB + 4194304;           // 16384*1024*4 = 67108864
    const size_t OFF_BIASN = OFF_COUT + 67108864;        // 4096
    const size_t OFF_PART  = OFF_BIASN + 4096;           // 808*2*4

    unsigned short* wB   = (unsigned short*)(ws + OFF_WB);
    float* Cout     = (float*)(ws + OFF_COUT);
    float* biasN    = (float*)(ws + OFF_BIASN);
    float* partials = (float*)(ws + OFF_PART);

    prep_weights<<<NBLK_PW, 256, 0, stream>>>(wmu, wrho, eps_w, wB, partials);
    prep_bias<<<1, 1024, 0, stream>>>(bmu, brho, eps_b, partials, biasN, out);
    gemm8<<<256, 512, 0, stream>>>(x, wB, biasN, Cout);
    stats_kernel<<<NB / 4, 256, 0, stream>>>(Cout, out);
}

// Round 4
// 144.988 us; speedup vs baseline: 1.4240x; 1.0294x over previous
//
#include <hip/hip_runtime.h>
#include <hip/hip_bf16.h>
#include <math.h>

#define NB    16384            // batch rows
#define KDIM  2048             // in_dim
#define NCLS  101              // classes
#define NP    10               // npass
#define NTOT  (NP*NCLS)        // 1010
#define NPAD  1024             // padded N for GEMM
#define PM_SIZE (NB*NCLS)
#define CI    (NCLS*KDIM)      // 206848
#define NBLK_PW ((CI + 255) / 256)   // 808 blocks in prep_weights
#define PAD_ELEMS ((NPAD - NTOT) * KDIM)  // 28672
#define NT    32               // K tiles of 64

#define LSQ2PI 0.9189385332046727f
#define HALF_INV_S2SQ 81377.39570642986f   // 0.5*exp(12) = 0.5/sigma2^2

typedef __bf16 bf16x8 __attribute__((ext_vector_type(8)));
typedef float f32x4 __attribute__((ext_vector_type(4)));

__device__ __forceinline__ unsigned short f2bf_bits(float f) {
    union { float f; unsigned u; } v; v.f = f;
    unsigned u = v.u;
    unsigned r = u + 0x7FFFu + ((u >> 16) & 1u);   // RNE
    return (unsigned short)(r >> 16);
}

__device__ __forceinline__ bf16x8 cvt8(float4 a, float4 b) {
    bf16x8 r;
    r[0] = (__bf16)a.x; r[1] = (__bf16)a.y; r[2] = (__bf16)a.z; r[3] = (__bf16)a.w;
    r[4] = (__bf16)b.x; r[5] = (__bf16)b.y; r[6] = (__bf16)b.z; r[7] = (__bf16)b.w;
    return r;
}

__device__ __forceinline__ float mix_logprob(float v) {
    float q = v * v;
    float lp1 = -LSQ2PI - 0.5f * q;
    float lp2 = -LSQ2PI + 6.0f - HALF_INV_S2SQ * q;
    return __logf(0.5f * __expf(lp1) + 0.5f * __expf(lp2));
}

// ------- sample w, write bf16 B-matrix, per-block partial prior/posterior -------
__global__ void prep_weights(const float* __restrict__ wmu, const float* __restrict__ wrho,
                             const float* __restrict__ eps_w,
                             unsigned short* __restrict__ wB, float* __restrict__ partials) {
    const int t = blockIdx.x * 256 + threadIdx.x;
    if (t < PAD_ELEMS) wB[(size_t)NTOT * KDIM + t] = 0;
    float prior = 0.f, post = 0.f;
    if (t < CI) {
        const float mu = wmu[t];
        const float sigma = log1pf(__expf(wrho[t]));
        const float nls = -__logf(sigma);
        const int c = t / KDIM, i = t & (KDIM - 1);
        #pragma unroll
        for (int n = 0; n < NP; ++n) {
            const float eps = eps_w[(size_t)n * CI + t];
            const float w = fmaf(sigma, eps, mu);
            wB[(size_t)(n * NCLS + c) * KDIM + i] = f2bf_bits(w);
            prior += mix_logprob(w);
            post += nls - LSQ2PI - 0.5f * eps * eps;
        }
    }
    for (int off = 32; off; off >>= 1) {
        prior += __shfl_xor(prior, off);
        post  += __shfl_xor(post, off);
    }
    __shared__ float sp[4], so[4];
    const int wid = threadIdx.x >> 6;
    if ((threadIdx.x & 63) == 0) { sp[wid] = prior; so[wid] = post; }
    __syncthreads();
    if (threadIdx.x == 0) {
        partials[blockIdx.x * 2]     = sp[0] + sp[1] + sp[2] + sp[3];
        partials[blockIdx.x * 2 + 1] = so[0] + so[1] + so[2] + so[3];
    }
}

// ------- sample b, build biasN[1024], reduce partials + bias terms, write scalars -------
__global__ void prep_bias(const float* __restrict__ bmu, const float* __restrict__ brho,
                          const float* __restrict__ eps_b, const float* __restrict__ partials,
                          float* __restrict__ biasN, float* __restrict__ out) {
    const int t = threadIdx.x;    // 1024 threads, 1 block
    float prior = 0.f, post = 0.f, bv = 0.f;
    if (t < NTOT) {
        const int c = t % NCLS;
        const float sigma = log1pf(__expf(brho[c]));
        const float eps = eps_b[t];
        bv = fmaf(sigma, eps, bmu[c]);
        prior = mix_logprob(bv);
        post = -LSQ2PI - __logf(sigma) - 0.5f * eps * eps;
    }
    biasN[t] = bv;
    if (t < NBLK_PW) { prior += partials[2 * t]; post += partials[2 * t + 1]; }
    for (int off = 32; off; off >>= 1) {
        prior += __shfl_xor(prior, off);
        post  += __shfl_xor(post, off);
    }
    __shared__ float sp[16], so[16];
    const int wid = t >> 6;
    if ((t & 63) == 0) { sp[wid] = prior; so[wid] = post; }
    __syncthreads();
    if (t == 0) {
        float a = 0.f, b = 0.f;
        for (int i = 0; i < 16; ++i) { a += sp[i]; b += so[i]; }
        out[PM_SIZE]     = a * (1.0f / NP);
        out[PM_SIZE + 1] = b * (1.0f / NP);
    }
}

// =============== 128x256 3-phase bf16 MFMA GEMM, fused f32->bf16, 2-deep A pipeline ===============
// BM=128, BN=256, BK=64, 512 threads (8 waves 2M x 4N, per-wave 64x64 output).
// LDS 96 KiB: A dbuf 2x16KB @0, B dbuf 2x(2x16KB halves) @32768.
// A (x, f32): reg-staged 2 tiles deep. A(t+2) loaded to regs at t.P1 (4x float4),
// A(t+1) cvt+ds_write (swizzled) at t.P3 after vmcnt. B (bf16): global_load_lds
// 2 tiles deep, inverse-swizzled source, staged at t.P3 for t+2.
// vmcnt ledger per tile t (issue order: A(t+2)4 @P1; B(t+2)4 @P3-after-wait):
//   t.P3 wait A(t+1) done: newer = B(t+1)4 + A(t+2)4 = 8 -> vmcnt(8)
//   t.end wait B(t+1) done: newer = A(t+2)4 + B(t+2)4 = 8 -> vmcnt(8), +lgkmcnt(0)
// Tail: t=NT-2: P3 vmcnt(4), end vmcnt(0); t=NT-1: no waits/barrier.
__device__ __forceinline__ void stage_half(const unsigned short* __restrict__ G,
                                           int grow0, int k0, int lds_byte_base,
                                           int tid, char* ldsp) {
    #pragma unroll
    for (int l = 0; l < 2; ++l) {
        const int flat = l * 512 + tid;            // 16B slot 0..1023 (128 rows x 8)
        const int row = flat >> 3, j = flat & 7;
        const int jsw = j ^ (row & 7);
        const unsigned short* src = G + (size_t)(grow0 + row) * KDIM + k0 + jsw * 8;
        __builtin_amdgcn_global_load_lds(
            (const __attribute__((address_space(1))) void*)src,
            (__attribute__((address_space(3))) void*)(ldsp + lds_byte_base + flat * 16),
            16, 0, 0);
    }
}

#define STAGE_B2(buf, tt) do { \
    stage_half(Bm, bn,       (tt) * 64, 32768 + (buf) * 32768,         tid, ldsp); \
    stage_half(Bm, bn + 128, (tt) * 64, 32768 + (buf) * 32768 + 16384, tid, ldsp); \
} while (0)

#define A_LOAD(SET, tt) do { \
    const float* p_ = X + (size_t)(bm + arow) * KDIM + (tt) * 64 + acol; \
    SET[0] = *(const float4*)p_;        SET[1] = *(const float4*)(p_ + 4); \
    SET[2] = *(const float4*)(p_ + 8);  SET[3] = *(const float4*)(p_ + 12); \
} while (0)

#define A_WRITE(SET, dstbuf) do { \
    char* base_ = ldsp + (dstbuf) * 16384; \
    *(bf16x8*)(base_ + aw0) = cvt8(SET[0], SET[1]); \
    *(bf16x8*)(base_ + aw1) = cvt8(SET[2], SET[3]); \
} while (0)

#define LDA(mf, buf) do { \
    const int row_ = wr * 64 + (mf) * 16 + l15; \
    const char* p_ = ldsp + (buf) * 16384 + row_ * 128; \
    const int sw_ = (row_ & 7) << 4; \
    af[mf][0] = *(const bf16x8*)(p_ + ((l4 << 4) ^ sw_)); \
    af[mf][1] = *(const bf16x8*)(p_ + (((4 + l4) << 4) ^ sw_)); \
} while (0)

#define LDB(nf, buf) do { \
    const int row_ = (wc & 1) * 64 + (nf) * 16 + l15; \
    const char* p_ = ldsp + 32768 + (buf) * 32768 + (wc >> 1) * 16384 + row_ * 128; \
    const int sw_ = (row_ & 7) << 4; \
    bf[nf][0] = *(const bf16x8*)(p_ + ((l4 << 4) ^ sw_)); \
    bf[nf][1] = *(const bf16x8*)(p_ + (((4 + l4) << 4) ^ sw_)); \
} while (0)

#define MM(mp, np) do { \
    __builtin_amdgcn_s_setprio(1); \
    _Pragma("unroll") \
    for (int mi = 0; mi < 2; ++mi) \
        _Pragma("unroll") \
        for (int ni = 0; ni < 2; ++ni) \
            _Pragma("unroll") \
            for (int kk = 0; kk < 2; ++kk) \
                acc[(mp) * 2 + mi][(np) * 2 + ni] = __builtin_amdgcn_mfma_f32_16x16x32_bf16( \
                    af[(mp) * 2 + mi][kk], bf[(np) * 2 + ni][kk], acc[(mp) * 2 + mi][(np) * 2 + ni], 0, 0, 0); \
    __builtin_amdgcn_s_setprio(0); \
} while (0)

#define SBAR() do { \
    __builtin_amdgcn_sched_barrier(0); \
    __builtin_amdgcn_s_barrier(); \
    __builtin_amdgcn_sched_barrier(0); \
} while (0)

#define TILE(t, buf, LSET, WSET) do { \
    /* P1: read af01 bf01; issue A(t+2) reg loads */ \
    LDA(0, buf); LDA(1, buf); \
    LDB(0, buf); LDB(1, buf); \
    if ((t) < NT - 2) { A_LOAD(LSET, (t) + 2); } \
    SBAR(); \
    MM(0, 0); \
    SBAR(); \
    /* P2: read bf23 */ \
    LDB(2, buf); LDB(3, buf); \
    SBAR(); \
    MM(0, 1); \
    SBAR(); \
    /* P3: read af23; wait A(t+1); write A(t+1); stage B(t+2); 16 MFMA */ \
    LDA(2, buf); LDA(3, buf); \
    __builtin_amdgcn_sched_barrier(0); \
    if ((t) < NT - 2)        { asm volatile("s_waitcnt vmcnt(8)"); } \
    else if ((t) == NT - 2)  { asm volatile("s_waitcnt vmcnt(4)"); } \
    __builtin_amdgcn_sched_barrier(0); \
    if ((t) < NT - 1) { A_WRITE(WSET, (buf) ^ 1); } \
    if ((t) < NT - 2) { STAGE_B2(buf, (t) + 2); } \
    SBAR(); \
    MM(1, 1); \
    MM(1, 0); \
    __builtin_amdgcn_sched_barrier(0); \
    if ((t) < NT - 2)        { asm volatile("s_waitcnt vmcnt(8) lgkmcnt(0)"); __builtin_amdgcn_s_barrier(); } \
    else if ((t) == NT - 2)  { asm volatile("s_waitcnt vmcnt(0) lgkmcnt(0)"); __builtin_amdgcn_s_barrier(); } \
    __builtin_amdgcn_sched_barrier(0); \
} while (0)

__global__ void __launch_bounds__(512, 2) gemm8(
    const float* __restrict__ X,             // [NB, KDIM] f32
    const unsigned short* __restrict__ Bm,   // [NPAD, KDIM] bf16 bits
    const float* __restrict__ biasN,
    float* __restrict__ Cout)                // [NB, NPAD] f32
{
    __shared__ __align__(16) unsigned short lds[49152];   // 96 KiB
    char* ldsp = (char*)lds;
    const int tid = threadIdx.x;
    const int lane = tid & 63, wid = tid >> 6;
    const int wr = wid >> 2, wc = wid & 3;               // 2M x 4N waves
    const int l15 = lane & 15, l4 = lane >> 4;

    const int b = blockIdx.x;                            // 512 blocks
    const int wg = (b & 7) * 64 + (b >> 3);              // bijective XCD swizzle
    const int bm = (wg >> 2) * 128;
    const int bn = (wg & 3) * 256;

    // A staging geometry: thread covers 64 consecutive bytes of one row:
    // slots s0=2*tid, s1=2*tid+1 (same row, adjacent 8-f32 groups)
    const int arow = tid >> 2;                           // 0..127
    const int acol = (tid & 3) * 16;                     // f32 col offset
    const int j0 = (2 * tid) & 7, j1 = j0 + 1;
    const int aw0 = arow * 128 + ((j0 ^ (arow & 7)) << 4);
    const int aw1 = arow * 128 + ((j1 ^ (arow & 7)) << 4);

    f32x4 acc[4][4] = {{}};
    bf16x8 af[4][2], bf[4][2];
    float4 aR0[4], aR1[4];

    // ---- prologue: A(0)->aR0, B(0); A(1)->aR1, B(1)
    A_LOAD(aR0, 0);
    STAGE_B2(0, 0);
    A_LOAD(aR1, 1);
    STAGE_B2(1, 1);
    __builtin_amdgcn_sched_barrier(0);
    asm volatile("s_waitcnt vmcnt(12)");     // A(0) done
    __builtin_amdgcn_sched_barrier(0);
    A_WRITE(aR0, 0);
    __builtin_amdgcn_sched_barrier(0);
    asm volatile("s_waitcnt vmcnt(8) lgkmcnt(0)");   // B(0) landed, A(0) write drained
    __builtin_amdgcn_s_barrier();
    __builtin_amdgcn_sched_barrier(0);

    #pragma unroll 1
    for (int tt = 0; tt < NT / 2; ++tt) {
        const int t0 = 2 * tt;
        TILE(t0,     0, aR0, aR1);   // A(t0+2)->set0; write A(t0+1) from set1
        TILE(t0 + 1, 1, aR1, aR0);   // A(t0+3)->set1; write A(t0+2) from set0
    }

    // ---- epilogue: bias + store f32 (C frag: col=lane&15, row=(lane>>4)*4+r)
    #pragma unroll
    for (int n = 0; n < 4; ++n) {
        const int col = bn + wc * 64 + n * 16 + l15;
        const float bv = biasN[col];
        #pragma unroll
        for (int m = 0; m < 4; ++m) {
            const int row0 = bm + wr * 64 + m * 16 + l4 * 4;
            #pragma unroll
            for (int r = 0; r < 4; ++r)
                Cout[(size_t)(row0 + r) * NPAD + col] = acc[m][n][r] + bv;
        }
    }
}

// ---------------- softmax stats: one wave per batch row ----------------
__global__ void stats_kernel(const float* __restrict__ Cout, float* __restrict__ out) {
    const int lane = threadIdx.x & 63;
    const int wid = threadIdx.x >> 6;
    const int b = blockIdx.x * 4 + wid;
    const float* row = Cout + (size_t)b * NPAD;
    float* pm = out;
    float* aleat_out = out + PM_SIZE + 2;
    float* epi_out   = out + PM_SIZE + 2 + NB;

    const bool has2 = lane < (NCLS - 64);
    float p1s[NP], p2s[NP];
    float pm1 = 0.f, pm2 = 0.f, pb1 = 0.f, pb2 = 0.f, aleat = 0.f;

    for (int n = 0; n < NP; ++n) {
        const float v1 = row[n * NCLS + lane];
        const float v2 = has2 ? row[n * NCLS + 64 + lane] : -INFINITY;
        float mx = fmaxf(v1, v2);
        for (int off = 32; off; off >>= 1) mx = fmaxf(mx, __shfl_xor(mx, off));
        const float e1 = __expf(v1 - mx);
        const float e2 = has2 ? __expf(v2 - mx) : 0.f;
        float s = e1 + e2;
        for (int off = 32; off; off >>= 1) s += __shfl_xor(s, off);
        const float p1 = e1 / s, p2 = e2 / s;
        float spp = p1 + p2, sq = p1 * p1 + p2 * p2;
        for (int off = 32; off; off >>= 1) {
            spp += __shfl_xor(spp, off);
            sq  += __shfl_xor(sq, off);
        }
        aleat += spp - sq;
        pm1 += v1; pm2 += v2;
        pb1 += p1; pb2 += p2;
        p1s[n] = p1; p2s[n] = p2;
    }
    const float inv_n = 1.0f / NP;
    pb1 *= inv_n; pb2 *= inv_n;
    pm[(size_t)b * NCLS + lane] = pm1 * inv_n;
    if (has2) pm[(size_t)b * NCLS + 64 + lane] = pm2 * inv_n;
    float epi = 0.f;
    #pragma unroll
    for (int n = 0; n < NP; ++n) {
        const float d1 = p1s[n] - pb1;
        const float d2 = p2s[n] - pb2;
        epi += d1 * d1 + d2 * d2;
    }
    for (int off = 32; off; off >>= 1) epi += __shfl_xor(epi, off);
    if (lane == 0) {
        aleat_out[b] = aleat * inv_n;
        epi_out[b]   = epi * inv_n;
    }
}

extern "C" void kernel_launch(void* const* d_in, const int* in_sizes, int n_in,
                              void* d_out, int out_size, void* d_ws, size_t ws_size,
                              hipStream_t stream) {
    const float* x     = (const float*)d_in[0];
    const float* wmu   = (const float*)d_in[1];
    const float* wrho  = (const float*)d_in[2];
    const float* bmu   = (const float*)d_in[3];
    const float* brho  = (const float*)d_in[4];
    const float* eps_w = (const float*)d_in[5];
    const float* eps_b = (const float*)d_in[6];
    float* out = (float*)d_out;

    char* ws = (char*)d_ws;
    const size_t OFF_WB    = 0;                          // 1024*2048*2  = 4194304
    const size_t OFF_COUT  = OFF_WB + 4194304;           // 16384*1024*4 = 67108864
    const size_t OFF_BIASN = OFF_COUT + 67108864;        // 4096
    const size_t OFF_PART  = OFF_BIASN + 4096;           // 808*2*4

    unsigned short* wB   = (unsigned short*)(ws + OFF_WB);
    float* Cout     = (float*)(ws + OFF_COUT);
    float* biasN    = (float*)(ws + OFF_BIASN);
    float* partials = (float*)(ws + OFF_PART);

    prep_weights<<<NBLK_PW, 256, 0, stream>>>(wmu, wrho, eps_w, wB, partials);
    prep_bias<<<1, 1024, 0, stream>>>(bmu, brho, eps_b, partials, biasN, out);
    gemm8<<<512, 512, 0, stream>>>(x, wB, biasN, Cout);
    stats_kernel<<<NB / 4, 256, 0, stream>>>(Cout, out);
}